// Round 5
// baseline (384.159 us; speedup 1.0000x reference)
//
#include <hip/hip_runtime.h>

#define H 1024
#define B 64
#define L 1024

typedef float vf4 __attribute__((ext_vector_type(4)));

// ---------------------------------------------------------------------------
// Kernel A: v[b,h] = sum_g hidden[b,g] * W[g,h]   (v = hidden @ W, 64x1024)
// Split-K: grid = B * (H/64) = 1024 blocks, 256 threads (4 waves).
// Wave `seg` accumulates g in [seg*256, seg*256+256); LDS combine.
// ---------------------------------------------------------------------------
__global__ __launch_bounds__(256) void proj_hidden_kernel(
    const float* __restrict__ hidden,
    const float* __restrict__ W,
    float* __restrict__ v) {
    __shared__ float sh[H];
    __shared__ float part[4][64];
    const int bid = blockIdx.x;
    const int b   = bid >> 4;          // / (H/64)
    const int h0  = (bid & 15) << 6;   // * 64
    const int tid = threadIdx.x;
    const int hl  = tid & 63;
    const int seg = tid >> 6;          // wave id = g-segment

    for (int i = tid; i < H; i += 256) sh[i] = hidden[b * H + i];
    __syncthreads();

    const int h = h0 + hl;
    const float* __restrict__ Wp = W + (size_t)(seg * 256) * H + h;
    const float* __restrict__ sp = sh + seg * 256;
    float acc = 0.f;
#pragma unroll 8
    for (int g = 0; g < 256; ++g) {
        acc += sp[g] * Wp[(size_t)g * H];   // sh read is wave-uniform broadcast
    }
    part[seg][hl] = acc;
    __syncthreads();
    if (tid < 64) {
        v[b * H + h0 + tid] =
            part[0][tid] + part[1][tid] + part[2][tid] + part[3][tid];
    }
}

// ---------------------------------------------------------------------------
// Kernel B: e[b,l] = dot(v[b,:], enc[l,b,:])
// One wave per (b, 4 consecutive l). v[b,:] held in 16 VGPRs, reused over
// 4 enc rows. ALL 16 enc loads (4 rows x 4 float4/lane) are issued before
// any FMA -> 256 B/lane guaranteed in flight (MLP), plain (cached) loads:
// the m13 6.29 TB/s streaming ceiling was measured WITHOUT nontemporal.
// Coalescing: each row read is 4KB contiguous; 4 waves/block have
// consecutive b -> 16KB contiguous span per row index j.
// ---------------------------------------------------------------------------
__global__ __launch_bounds__(256) void energy_kernel(
    const float* __restrict__ enc,
    const float* __restrict__ v,
    float* __restrict__ e) {
    const int wave = (blockIdx.x * 256 + threadIdx.x) >> 6;
    const int lane = threadIdx.x & 63;
    const int b  = wave & (B - 1);
    const int l0 = (wave >> 6) << 2;   // 4 l-values per wave

    const vf4* __restrict__ vp = reinterpret_cast<const vf4*>(v + (size_t)b * H);
    const vf4 w0 = vp[lane], w1 = vp[lane + 64], w2 = vp[lane + 128], w3 = vp[lane + 192];

    // Issue all 16 loads first (independent addresses -> 16 outstanding).
    vf4 a[4][4];
#pragma unroll
    for (int j = 0; j < 4; ++j) {
        const vf4* __restrict__ ep =
            reinterpret_cast<const vf4*>(enc + ((size_t)(l0 + j) * B + b) * H);
#pragma unroll
        for (int k = 0; k < 4; ++k) a[j][k] = ep[lane + k * 64];
    }

    float acc[4];
#pragma unroll
    for (int j = 0; j < 4; ++j) {
        acc[j] = a[j][0].x * w0.x + a[j][0].y * w0.y + a[j][0].z * w0.z + a[j][0].w * w0.w
               + a[j][1].x * w1.x + a[j][1].y * w1.y + a[j][1].z * w1.z + a[j][1].w * w1.w
               + a[j][2].x * w2.x + a[j][2].y * w2.y + a[j][2].z * w2.z + a[j][2].w * w2.w
               + a[j][3].x * w3.x + a[j][3].y * w3.y + a[j][3].z * w3.z + a[j][3].w * w3.w;
    }
#pragma unroll
    for (int off = 32; off; off >>= 1) {
#pragma unroll
        for (int j = 0; j < 4; ++j) acc[j] += __shfl_down(acc[j], off, 64);
    }
    if (lane == 0) {
#pragma unroll
        for (int j = 0; j < 4; ++j) e[(size_t)b * L + l0 + j] = acc[j];
    }
}

// ---------------------------------------------------------------------------
// Kernel C: row softmax over L=1024 per batch. 64 blocks x 1024 threads.
// (Bias term c[b] omitted: softmax is invariant to a per-row constant.)
// ---------------------------------------------------------------------------
__global__ __launch_bounds__(1024) void softmax_kernel(
    const float* __restrict__ e,
    float* __restrict__ out) {
    const int b = blockIdx.x;
    const int tid = threadIdx.x;
    const int wid = tid >> 6, lane = tid & 63;
    __shared__ float red[16];

    float x = e[(size_t)b * L + tid];

    float m = x;
#pragma unroll
    for (int off = 32; off; off >>= 1) m = fmaxf(m, __shfl_down(m, off, 64));
    if (lane == 0) red[wid] = m;
    __syncthreads();
    if (tid < 16) {
        float t = red[tid];
#pragma unroll
        for (int off = 8; off; off >>= 1) t = fmaxf(t, __shfl_down(t, off, 16));
        if (tid == 0) red[0] = t;
    }
    __syncthreads();
    m = red[0];
    __syncthreads();

    float ex = __expf(x - m);
    float s = ex;
#pragma unroll
    for (int off = 32; off; off >>= 1) s += __shfl_down(s, off, 64);
    if (lane == 0) red[wid] = s;
    __syncthreads();
    if (tid < 16) {
        float t = red[tid];
#pragma unroll
        for (int off = 8; off; off >>= 1) t += __shfl_down(t, off, 16);
        if (tid == 0) red[0] = t;
    }
    __syncthreads();
    s = red[0];

    out[(size_t)b * L + tid] = ex / s;
}

extern "C" void kernel_launch(void* const* d_in, const int* in_sizes, int n_in,
                              void* d_out, int out_size, void* d_ws, size_t ws_size,
                              hipStream_t stream) {
    const float* hidden = (const float*)d_in[0];   // (1, B, H)
    const float* enc    = (const float*)d_in[1];   // (L, B, H)
    const float* W      = (const float*)d_in[2];   // (H, H)
    // d_in[3] = bias — unused: softmax is invariant to per-row constants.
    float* out = (float*)d_out;                    // (B, 1, L)

    float* v = (float*)d_ws;        // B*H floats = 256 KB
    float* e = v + (size_t)B * H;   // B*L floats = 256 KB

    proj_hidden_kernel<<<B * (H / 64), 256, 0, stream>>>(hidden, W, v);
    energy_kernel<<<(B * L / 4) / 4, 256, 0, stream>>>(enc, v, e);
    softmax_kernel<<<B, 1024, 0, stream>>>(e, out);
}